// Round 1
// baseline (2056.142 us; speedup 1.0000x reference)
//
#include <hip/hip_runtime.h>

typedef short bf16x8 __attribute__((ext_vector_type(8)));
typedef unsigned short u16x8 __attribute__((ext_vector_type(8)));
typedef unsigned short u16x4 __attribute__((ext_vector_type(4)));
typedef float f32x4 __attribute__((ext_vector_type(4)));
typedef unsigned short u16;

#define N_TOK 49
#define NN    2401
#define DIM   256
#define NWIN  1024
#define QK_S  40
#define VT_S  72
#define P_S   72
#define OH_S  40

// ---- legacy (mid-tier) bf16 ws layout (u16 offsets) ----
#define WS_MASK_OFF   0ull
#define WS_QKVW_OFF   2458624ull                  // 1024*49*49
#define WS_PROJW_OFF  (WS_QKVW_OFF + 196608ull)   // 768*256
#define WS_QKVB_OFF   (WS_PROJW_OFF + 65536ull)   // 256*256
#define WS_PROJB_OFF  (WS_QKVB_OFF + 768ull)
#define WS_RPB_OFF    (WS_PROJB_OFF + 256ull)
#define WS_TOT_U16    (WS_RPB_OFF + 1352ull)

// ---- v2 ws layout: combined (mask + rel-pos-bias) per (win,h,m,n), then weights ----
#define C2_CMB_OFF    0ull                         // 1024*8*2401 u16
#define C2_QKVW_OFF   (1024ull * 8ull * NN)        // 19,668,992
#define C2_PROJW_OFF  (C2_QKVW_OFF + 196608ull)
#define C2_QKVB_OFF   (C2_PROJW_OFF + 65536ull)
#define C2_PROJB_OFF  (C2_QKVB_OFF + 768ull)
#define C2_TOT_U16    (C2_PROJB_OFF + 256ull)      // 19,932,160 u16 = ~38 MB

__device__ __forceinline__ float bf2f(u16 b) {
  unsigned int u = ((unsigned int)b) << 16;
  return __builtin_bit_cast(float, u);
}
__device__ __forceinline__ u16 f2bf(float f) {
  unsigned int u = __builtin_bit_cast(unsigned int, f);
  return (u16)((u + 0x7fffu + ((u >> 16) & 1u)) >> 16);
}
__device__ __forceinline__ float lde(const void* p, size_t i, bool isbf) {
  return isbf ? bf2f(((const u16*)p)[i]) : ((const float*)p)[i];
}
__device__ __forceinline__ bf16x8 cvt8(const float* f) {
  f32x4 a = *(const f32x4*)f;
  f32x4 b = *(const f32x4*)(f + 4);
  u16x8 r;
  r[0]=f2bf(a[0]); r[1]=f2bf(a[1]); r[2]=f2bf(a[2]); r[3]=f2bf(a[3]);
  r[4]=f2bf(b[0]); r[5]=f2bf(b[1]); r[6]=f2bf(b[2]); r[7]=f2bf(b[3]);
  return __builtin_bit_cast(bf16x8, r);
}
// wave-uniform dtype probe: true if tensor looks like bf16
__device__ __forceinline__ bool probe_bf(const void* p) {
  int lane = threadIdx.x & 63;
  u16 h = ((const u16*)p)[2 * lane];
  int e = (h >> 7) & 0xFF;
  bool sane = ((h & 0x7fffu) == 0) || (e >= 96 && e <= 140);
  return (__ballot(!sane) == 0ull);
}

// ---- pre-pass: convert one float tensor (fp32 or bf16) to bf16 in ws ----
__global__ void cvt_kernel(const void* __restrict__ src, u16* __restrict__ dst, int n) {
  bool isbf = probe_bf(src);
  int i = blockIdx.x * 256 + threadIdx.x;
  if (i < n)
    dst[i] = isbf ? ((const u16*)src)[i] : f2bf(((const float*)src)[i]);
}

// ---- pre-pass: combined[win][h][m][n] = mask[win][m][n] + rpb[rel_idx[m][n]][h] ----
__global__ void build_bias_kernel(const void* __restrict__ mask, const void* __restrict__ rpb,
                                  const int* __restrict__ rel_idx, u16* __restrict__ dst) {
  __shared__ float msk[NN];
  __shared__ float rp[169 * 8];
  const int win = blockIdx.x;
  const bool bm = probe_bf(mask);
  const bool br = probe_bf(rpb);
  for (int i = threadIdx.x; i < NN; i += 256) msk[i] = lde(mask, (size_t)win * NN + i, bm);
  for (int i = threadIdx.x; i < 169 * 8; i += 256) rp[i] = lde(rpb, i, br);
  __syncthreads();
  u16* dw = dst + (size_t)win * (8ull * NN);
  for (int i = threadIdx.x; i < 8 * NN; i += 256) {
    int h = i / NN, mn = i % NN;
    dw[i] = f2bf(msk[mn] + rp[rel_idx[mn] * 8 + h]);
  }
}

__global__ __launch_bounds__(256, 3)
void winattn_kernel(const void* __restrict__ x, const void* __restrict__ mask,
                    const void* __restrict__ qkv_w, const void* __restrict__ qkv_b,
                    const void* __restrict__ proj_w, const void* __restrict__ proj_b,
                    const void* __restrict__ rpb, const int* __restrict__ rel_idx,
                    void* __restrict__ out, const u16* __restrict__ wsu, int mode)
{
  // double-buffered cross-wave buffers; Ps/oh are same-wave-only (no dbuf, no barrier)
  __shared__ u16 qs [2][64 * QK_S];
  __shared__ u16 ksm[2][64 * QK_S];
  __shared__ u16 vT [2][32 * VT_S];
  __shared__ u16 Ps [64 * P_S];
  __shared__ u16 oh [64 * OH_S];

  const int tid  = threadIdx.x;
  const int wv   = tid >> 6;
  const int lane = tid & 63;
  const int quad = lane >> 4;
  const int l15  = lane & 15;
  const int w    = blockIdx.x;

  const bool bx = probe_bf(x);
  bool bm = true, bw = true, bqb = true, bpw = true, bpb = true, brp = true;
  if (mode == 0) {
    bm = probe_bf(mask); bw = probe_bf(qkv_w); bqb = probe_bf(qkv_b);
    bpw = probe_bf(proj_w); bpb = probe_bf(proj_b); brp = probe_bf(rpb);
  }

  const void* mask_p = (mode == 1) ? (const void*)(wsu + WS_MASK_OFF) : mask;
  const void* rpb_p  = (mode == 1) ? (const void*)(wsu + WS_RPB_OFF)  : rpb;
  const void* qkvw_p = (mode == 2) ? (const void*)(wsu + C2_QKVW_OFF)
                     : (mode == 1) ? (const void*)(wsu + WS_QKVW_OFF) : qkv_w;
  const void* qkvb_p = (mode == 2) ? (const void*)(wsu + C2_QKVB_OFF)
                     : (mode == 1) ? (const void*)(wsu + WS_QKVB_OFF) : qkv_b;
  const void* pjw_p  = (mode == 2) ? (const void*)(wsu + C2_PROJW_OFF)
                     : (mode == 1) ? (const void*)(wsu + WS_PROJW_OFF) : proj_w;
  const void* pjb_p  = (mode == 2) ? (const void*)(wsu + C2_PROJB_OFF)
                     : (mode == 1) ? (const void*)(wsu + WS_PROJB_OFF) : proj_b;

  // ---- x A-fragments live in registers: this wave's 16 rows, all 256 cols ----
  bf16x8 xf[8];
  {
    const int row = 16 * wv + l15;
    if (row < N_TOK) {
      if (bx) {
        const u16* xw = (const u16*)x + (size_t)w * (N_TOK * DIM) + row * DIM + quad * 8;
        #pragma unroll
        for (int ks = 0; ks < 8; ++ks) xf[ks] = *(const bf16x8*)(xw + ks * 32);
      } else {
        const float* xw = (const float*)x + (size_t)w * (N_TOK * DIM) + row * DIM + quad * 8;
        #pragma unroll
        for (int ks = 0; ks < 8; ++ks) xf[ks] = cvt8(xw + ks * 32);
      }
    } else {
      const bf16x8 z = {0, 0, 0, 0, 0, 0, 0, 0};
      #pragma unroll
      for (int ks = 0; ks < 8; ++ks) xf[ks] = z;
    }
  }

  f32x4 pacc[16];
  #pragma unroll
  for (int i = 0; i < 16; ++i) pacc[i] = (f32x4){0.f, 0.f, 0.f, 0.f};

  const int    mrow = 16 * wv + quad * 4;
  const size_t moff = (size_t)(w & (NWIN - 1)) * NN;
  const u16*   cmbw = wsu + C2_CMB_OFF + (size_t)(w & (NWIN - 1)) * (8ull * NN);

  #pragma unroll 1
  for (int h = 0; h < 8; ++h) {
    u16* qsb = qs[h & 1];
    u16* ksb = ksm[h & 1];
    u16* vtb = vT[h & 1];

    // ---- combined bias preload: issues at top of body, overlaps the QKV GEMM ----
    float cb[4][4];
    if (mode == 2) {
      const u16* cp = cmbw + (size_t)h * NN;
      #pragma unroll
      for (int r = 0; r < 4; ++r) {
        const int m = mrow + r;
        #pragma unroll
        for (int ni = 0; ni < 4; ++ni) {
          const int n = ni * 16 + l15;
          cb[r][ni] = (m < N_TOK && n < N_TOK) ? bf2f(cp[m * N_TOK + n]) : 0.f;
        }
      }
    } else {
      #pragma unroll
      for (int r = 0; r < 4; ++r) {
        const int m = mrow + r;
        #pragma unroll
        for (int ni = 0; ni < 4; ++ni) {
          const int n = ni * 16 + l15;
          float c = 0.f;
          if (m < N_TOK && n < N_TOK) {
            int idx = rel_idx[m * N_TOK + n];
            c = lde(rpb_p, (size_t)idx * 8 + h, brp) + lde(mask_p, moff + m * N_TOK + n, bm);
          }
          cb[r][ni] = c;
        }
      }
    }

    // ================= QKV GEMM (A from registers) =================
    f32x4 acc[6];
    #pragma unroll
    for (int j = 0; j < 6; ++j) acc[j] = (f32x4){0.f, 0.f, 0.f, 0.f};
    const int nb0 = h * 32;
    if (bw) {
      const u16* wp = (const u16*)qkvw_p;
      #pragma unroll
      for (int ks = 0; ks < 8; ++ks) {
        bf16x8 a = xf[ks];
        #pragma unroll
        for (int j = 0; j < 6; ++j) {
          int n = (j >> 1) * 256 + nb0 + (j & 1) * 16 + l15;
          bf16x8 b = *(const bf16x8*)(wp + (size_t)n * DIM + ks * 32 + quad * 8);
          acc[j] = __builtin_amdgcn_mfma_f32_16x16x32_bf16(a, b, acc[j], 0, 0, 0);
        }
      }
    } else {
      const float* wp = (const float*)qkvw_p;
      #pragma unroll
      for (int ks = 0; ks < 8; ++ks) {
        bf16x8 a = xf[ks];
        #pragma unroll
        for (int j = 0; j < 6; ++j) {
          int n = (j >> 1) * 256 + nb0 + (j & 1) * 16 + l15;
          bf16x8 b = cvt8(wp + (size_t)n * DIM + ks * 32 + quad * 8);
          acc[j] = __builtin_amdgcn_mfma_f32_16x16x32_bf16(a, b, acc[j], 0, 0, 0);
        }
      }
    }
    // write q (scaled,+bias), k (+bias), vT (+bias, transposed)
    {
      const float scale = 0.1767766952966369f;   // 1/sqrt(32)
      #pragma unroll
      for (int j = 0; j < 6; ++j) {
        int   n    = (j >> 1) * 256 + nb0 + (j & 1) * 16 + l15;
        float bias = lde(qkvb_p, n, bqb);
        int   lc   = (j & 1) * 16 + l15;
        if (j < 2) {
          #pragma unroll
          for (int r = 0; r < 4; ++r)
            qsb[(mrow + r) * QK_S + lc] = f2bf((acc[j][r] + bias) * scale);
        } else if (j < 4) {
          #pragma unroll
          for (int r = 0; r < 4; ++r)
            ksb[(mrow + r) * QK_S + lc] = f2bf(acc[j][r] + bias);
        } else {
          u16x4 pk;
          #pragma unroll
          for (int r = 0; r < 4; ++r) pk[r] = f2bf(acc[j][r] + bias);
          *(u16x4*)&vtb[lc * VT_S + mrow] = pk;
        }
      }
    }
    __syncthreads();   // the only barrier per head (q/k/vT dbuf'd across heads)

    // ================= S = q k^T =================
    f32x4 s[4];
    {
      bf16x8 aq = *(const bf16x8*)&qsb[(16 * wv + l15) * QK_S + quad * 8];
      #pragma unroll
      for (int ni = 0; ni < 4; ++ni) {
        bf16x8 bk = *(const bf16x8*)&ksb[(ni * 16 + l15) * QK_S + quad * 8];
        s[ni] = __builtin_amdgcn_mfma_f32_16x16x32_bf16(aq, bk, (f32x4){0.f,0.f,0.f,0.f}, 0, 0, 0);
      }
    }
    // bias+mask (preloaded) + softmax (row = 16-lane quad-group)
    float rs[4];
    #pragma unroll
    for (int r = 0; r < 4; ++r) {
      #pragma unroll
      for (int ni = 0; ni < 4; ++ni) {
        int   n = ni * 16 + l15;
        float v = s[ni][r];
        s[ni][r] = (n >= N_TOK) ? -1e30f : v + cb[r][ni];
      }
      float mx = fmaxf(fmaxf(s[0][r], s[1][r]), fmaxf(s[2][r], s[3][r]));
      #pragma unroll
      for (int d2 = 1; d2 < 16; d2 <<= 1) mx = fmaxf(mx, __shfl_xor(mx, d2));
      float sum = 0.f;
      #pragma unroll
      for (int ni = 0; ni < 4; ++ni) {
        float p = __expf(s[ni][r] - mx);
        s[ni][r] = p;
        sum += p;
      }
      #pragma unroll
      for (int d2 = 1; d2 < 16; d2 <<= 1) sum += __shfl_xor(sum, d2);
      rs[r] = sum;
      #pragma unroll
      for (int ni = 0; ni < 4; ++ni)
        Ps[(mrow + r) * P_S + ni * 16 + l15] = f2bf(s[ni][r]);
    }

    // ================= O = P V =================
    f32x4 o0 = {0.f,0.f,0.f,0.f}, o1 = {0.f,0.f,0.f,0.f};
    #pragma unroll
    for (int ks = 0; ks < 2; ++ks) {
      bf16x8 ap = *(const bf16x8*)&Ps[(16 * wv + l15) * P_S + ks * 32 + quad * 8];
      bf16x8 b0 = *(const bf16x8*)&vtb[(l15)      * VT_S + ks * 32 + quad * 8];
      bf16x8 b1 = *(const bf16x8*)&vtb[(16 + l15) * VT_S + ks * 32 + quad * 8];
      o0 = __builtin_amdgcn_mfma_f32_16x16x32_bf16(ap, b0, o0, 0, 0, 0);
      o1 = __builtin_amdgcn_mfma_f32_16x16x32_bf16(ap, b1, o1, 0, 0, 0);
    }
    #pragma unroll
    for (int r = 0; r < 4; ++r) {
      float inv = 1.f / rs[r];
      oh[(mrow + r) * OH_S + l15]      = f2bf(o0[r] * inv);
      oh[(mrow + r) * OH_S + 16 + l15] = f2bf(o1[r] * inv);
    }

    // ================= proj partial =================
    {
      bf16x8 ao = *(const bf16x8*)&oh[(16 * wv + l15) * OH_S + quad * 8];
      if (bpw) {
        const u16* pp = (const u16*)pjw_p;
        #pragma unroll
        for (int ni = 0; ni < 16; ++ni) {
          bf16x8 bp = *(const bf16x8*)(pp + (size_t)(ni * 16 + l15) * DIM + h * 32 + quad * 8);
          pacc[ni] = __builtin_amdgcn_mfma_f32_16x16x32_bf16(ao, bp, pacc[ni], 0, 0, 0);
        }
      } else {
        const float* pp = (const float*)pjw_p;
        #pragma unroll
        for (int ni = 0; ni < 16; ++ni) {
          bf16x8 bp = cvt8(pp + (size_t)(ni * 16 + l15) * DIM + h * 32 + quad * 8);
          pacc[ni] = __builtin_amdgcn_mfma_f32_16x16x32_bf16(ao, bp, pacc[ni], 0, 0, 0);
        }
      }
    }
  }

  // ================= epilogue: + proj_b; output dtype follows x =================
  const size_t obase = (size_t)w * (N_TOK * DIM);
  if (bx) {
    u16* ow = (u16*)out + obase;
    #pragma unroll
    for (int r = 0; r < 4; ++r) {
      int m = mrow + r;
      if (m < N_TOK) {
        #pragma unroll
        for (int ni = 0; ni < 16; ++ni) {
          int col = ni * 16 + l15;
          ow[m * DIM + col] = f2bf(pacc[ni][r] + lde(pjb_p, col, bpb));
        }
      }
    }
  } else {
    float* ow = (float*)out + obase;
    #pragma unroll
    for (int r = 0; r < 4; ++r) {
      int m = mrow + r;
      if (m < N_TOK) {
        #pragma unroll
        for (int ni = 0; ni < 16; ++ni) {
          int col = ni * 16 + l15;
          ow[m * DIM + col] = pacc[ni][r] + lde(pjb_p, col, bpb);
        }
      }
    }
  }
}

extern "C" void kernel_launch(void* const* d_in, const int* in_sizes, int n_in,
                              void* d_out, int out_size, void* d_ws, size_t ws_size,
                              hipStream_t stream) {
  u16* wsu = (u16*)d_ws;
  int mode = 0;
  if (ws_size >= C2_TOT_U16 * 2) mode = 2;
  else if (ws_size >= WS_TOT_U16 * 2) mode = 1;

  auto cv = [&](const void* src, unsigned long long off, int n) {
    cvt_kernel<<<(n + 255) / 256, 256, 0, stream>>>(src, wsu + off, n);
  };

  if (mode == 2) {
    build_bias_kernel<<<NWIN, 256, 0, stream>>>(d_in[1], d_in[6], (const int*)d_in[7],
                                                wsu + C2_CMB_OFF);
    cv(d_in[2], C2_QKVW_OFF, 3 * DIM * DIM);
    cv(d_in[3], C2_QKVB_OFF, 3 * DIM);
    cv(d_in[4], C2_PROJW_OFF, DIM * DIM);
    cv(d_in[5], C2_PROJB_OFF, DIM);
  } else if (mode == 1) {
    cv(d_in[1], WS_MASK_OFF,  NWIN * N_TOK * N_TOK);
    cv(d_in[2], WS_QKVW_OFF,  3 * DIM * DIM);
    cv(d_in[3], WS_QKVB_OFF,  3 * DIM);
    cv(d_in[4], WS_PROJW_OFF, DIM * DIM);
    cv(d_in[5], WS_PROJB_OFF, DIM);
    cv(d_in[6], WS_RPB_OFF,   169 * 8);
  }
  winattn_kernel<<<4096, 256, 0, stream>>>(
      d_in[0], d_in[1], d_in[2], d_in[3], d_in[4], d_in[5], d_in[6],
      (const int*)d_in[7], d_out, wsu, mode);
}

// Round 2
// 1502.798 us; speedup vs baseline: 1.3682x; 1.3682x over previous
//
#include <hip/hip_runtime.h>

typedef short bf16x8 __attribute__((ext_vector_type(8)));
typedef unsigned short u16x8 __attribute__((ext_vector_type(8)));
typedef unsigned short u16x4 __attribute__((ext_vector_type(4)));
typedef float f32x4 __attribute__((ext_vector_type(4)));
typedef unsigned short u16;

#define N_TOK 49
#define NN    2401
#define DIM   256
#define NWIN  1024
#define QK_S  40
#define VT_S  72
#define P_S   72
#define OH_S  40

// ---- legacy (mid-tier) bf16 ws layout (u16 offsets) ----
#define WS_MASK_OFF   0ull
#define WS_QKVW_OFF   2458624ull                  // 1024*49*49
#define WS_PROJW_OFF  (WS_QKVW_OFF + 196608ull)   // 768*256
#define WS_QKVB_OFF   (WS_PROJW_OFF + 65536ull)   // 256*256
#define WS_PROJB_OFF  (WS_QKVB_OFF + 768ull)
#define WS_RPB_OFF    (WS_PROJB_OFF + 256ull)
#define WS_TOT_U16    (WS_RPB_OFF + 1352ull)

// ---- v2 ws layout: combined (mask + rel-pos-bias) per (win,h,m,n), then weights ----
#define C2_CMB_OFF    0ull                         // 1024*8*2401 u16
#define C2_QKVW_OFF   (1024ull * 8ull * NN)        // 19,668,992
#define C2_PROJW_OFF  (C2_QKVW_OFF + 196608ull)
#define C2_QKVB_OFF   (C2_PROJW_OFF + 65536ull)
#define C2_PROJB_OFF  (C2_QKVB_OFF + 768ull)
#define C2_TOT_U16    (C2_PROJB_OFF + 256ull)      // 19,932,160 u16 = ~38 MB

__device__ __forceinline__ float bf2f(u16 b) {
  unsigned int u = ((unsigned int)b) << 16;
  return __builtin_bit_cast(float, u);
}
__device__ __forceinline__ u16 f2bf(float f) {
  unsigned int u = __builtin_bit_cast(unsigned int, f);
  return (u16)((u + 0x7fffu + ((u >> 16) & 1u)) >> 16);
}
__device__ __forceinline__ float lde(const void* p, size_t i, bool isbf) {
  return isbf ? bf2f(((const u16*)p)[i]) : ((const float*)p)[i];
}
__device__ __forceinline__ bf16x8 cvt8(const float* f) {
  f32x4 a = *(const f32x4*)f;
  f32x4 b = *(const f32x4*)(f + 4);
  u16x8 r;
  r[0]=f2bf(a[0]); r[1]=f2bf(a[1]); r[2]=f2bf(a[2]); r[3]=f2bf(a[3]);
  r[4]=f2bf(b[0]); r[5]=f2bf(b[1]); r[6]=f2bf(b[2]); r[7]=f2bf(b[3]);
  return __builtin_bit_cast(bf16x8, r);
}
// wave-uniform dtype probe: true if tensor looks like bf16
__device__ __forceinline__ bool probe_bf(const void* p) {
  int lane = threadIdx.x & 63;
  u16 h = ((const u16*)p)[2 * lane];
  int e = (h >> 7) & 0xFF;
  bool sane = ((h & 0x7fffu) == 0) || (e >= 96 && e <= 140);
  return (__ballot(!sane) == 0ull);
}

// ---- pre-pass: convert one float tensor (fp32 or bf16) to bf16 in ws ----
__global__ void cvt_kernel(const void* __restrict__ src, u16* __restrict__ dst, int n) {
  bool isbf = probe_bf(src);
  int i = blockIdx.x * 256 + threadIdx.x;
  if (i < n)
    dst[i] = isbf ? ((const u16*)src)[i] : f2bf(((const float*)src)[i]);
}

// ---- pre-pass: combined[win][h][m][n] = mask[win][m][n] + rpb[rel_idx[m][n]][h] ----
__global__ void build_bias_kernel(const void* __restrict__ mask, const void* __restrict__ rpb,
                                  const int* __restrict__ rel_idx, u16* __restrict__ dst) {
  __shared__ float msk[NN];
  __shared__ float rp[169 * 8];
  const int win = blockIdx.x;
  const bool bm = probe_bf(mask);
  const bool br = probe_bf(rpb);
  for (int i = threadIdx.x; i < NN; i += 256) msk[i] = lde(mask, (size_t)win * NN + i, bm);
  for (int i = threadIdx.x; i < 169 * 8; i += 256) rp[i] = lde(rpb, i, br);
  __syncthreads();
  u16* dw = dst + (size_t)win * (8ull * NN);
  for (int i = threadIdx.x; i < 8 * NN; i += 256) {
    int h = i / NN, mn = i % NN;
    dw[i] = f2bf(msk[mn] + rp[rel_idx[mn] * 8 + h]);
  }
}

__global__ __launch_bounds__(256, 2)
void winattn_kernel(const void* __restrict__ x, const void* __restrict__ mask,
                    const void* __restrict__ qkv_w, const void* __restrict__ qkv_b,
                    const void* __restrict__ proj_w, const void* __restrict__ proj_b,
                    const void* __restrict__ rpb, const int* __restrict__ rel_idx,
                    void* __restrict__ out, const u16* __restrict__ wsu, int mode)
{
  // qs/Ps/oh are same-wave-only (write+read by owning wave): single buffer, no barrier.
  // ksm/vT cross waves: double-buffered so one barrier per head suffices.
  __shared__ u16 qs [64 * QK_S];
  __shared__ u16 ksm[2][64 * QK_S];
  __shared__ u16 vT [2][32 * VT_S];
  __shared__ u16 Ps [64 * P_S];
  __shared__ u16 oh [64 * OH_S];

  const int tid  = threadIdx.x;
  const int wv   = tid >> 6;
  const int lane = tid & 63;
  const int quad = lane >> 4;
  const int l15  = lane & 15;
  const int w    = blockIdx.x;

  const bool bx = probe_bf(x);
  bool bm = true, bw = true, bqb = true, bpw = true, bpb = true, brp = true;
  if (mode == 0) {
    bm = probe_bf(mask); bw = probe_bf(qkv_w); bqb = probe_bf(qkv_b);
    bpw = probe_bf(proj_w); bpb = probe_bf(proj_b); brp = probe_bf(rpb);
  }

  const void* mask_p = (mode == 1) ? (const void*)(wsu + WS_MASK_OFF) : mask;
  const void* rpb_p  = (mode == 1) ? (const void*)(wsu + WS_RPB_OFF)  : rpb;
  const void* qkvw_p = (mode == 2) ? (const void*)(wsu + C2_QKVW_OFF)
                     : (mode == 1) ? (const void*)(wsu + WS_QKVW_OFF) : qkv_w;
  const void* qkvb_p = (mode == 2) ? (const void*)(wsu + C2_QKVB_OFF)
                     : (mode == 1) ? (const void*)(wsu + WS_QKVB_OFF) : qkv_b;
  const void* pjw_p  = (mode == 2) ? (const void*)(wsu + C2_PROJW_OFF)
                     : (mode == 1) ? (const void*)(wsu + WS_PROJW_OFF) : proj_w;
  const void* pjb_p  = (mode == 2) ? (const void*)(wsu + C2_PROJB_OFF)
                     : (mode == 1) ? (const void*)(wsu + WS_PROJB_OFF) : proj_b;

  // ---- x A-fragments live in registers: this wave's 16 rows, all 256 cols ----
  bf16x8 xf[8];
  {
    const int row = 16 * wv + l15;
    if (row < N_TOK) {
      if (bx) {
        const u16* xw = (const u16*)x + (size_t)w * (N_TOK * DIM) + row * DIM + quad * 8;
        #pragma unroll
        for (int ks = 0; ks < 8; ++ks) xf[ks] = *(const bf16x8*)(xw + ks * 32);
      } else {
        const float* xw = (const float*)x + (size_t)w * (N_TOK * DIM) + row * DIM + quad * 8;
        #pragma unroll
        for (int ks = 0; ks < 8; ++ks) xf[ks] = cvt8(xw + ks * 32);
      }
    } else {
      const bf16x8 z = {0, 0, 0, 0, 0, 0, 0, 0};
      #pragma unroll
      for (int ks = 0; ks < 8; ++ks) xf[ks] = z;
    }
  }

  // per-head o A-fragments (named scalars, NOT a runtime-indexed array -> stay in VGPRs)
  bf16x8 oa0, oa1, oa2, oa3, oa4, oa5, oa6, oa7;

  const int    mrow = 16 * wv + quad * 4;
  const size_t moff = (size_t)(w & (NWIN - 1)) * NN;
  const u16*   cmbw = wsu + C2_CMB_OFF + (size_t)(w & (NWIN - 1)) * (8ull * NN);

  #pragma unroll 1
  for (int h = 0; h < 8; ++h) {
    u16* ksb = ksm[h & 1];
    u16* vtb = vT[h & 1];
    const int nb0 = h * 32;

    // ---- combined bias preload (packed 2xbf16 per u32: 8 VGPRs total) ----
    unsigned int cbp[4][2];
    if (mode == 2) {
      const u16* cp = cmbw + (size_t)h * NN;
      #pragma unroll
      for (int r = 0; r < 4; ++r) {
        const int m = mrow + r;
        u16 t0 = 0, t1 = 0, t2 = 0, t3 = 0;
        if (m < N_TOK) {
          const u16* rowp = cp + m * N_TOK + l15;
          t0 = rowp[0];
          t1 = rowp[16];
          t2 = rowp[32];
          if (48 + l15 < N_TOK) t3 = rowp[48];
        }
        cbp[r][0] = (unsigned)t0 | ((unsigned)t1 << 16);
        cbp[r][1] = (unsigned)t2 | ((unsigned)t3 << 16);
      }
    } else {
      #pragma unroll
      for (int r = 0; r < 4; ++r) {
        const int m = mrow + r;
        u16 t[4];
        #pragma unroll
        for (int ni = 0; ni < 4; ++ni) {
          const int n = ni * 16 + l15;
          float c = 0.f;
          if (m < N_TOK && n < N_TOK) {
            int idx = rel_idx[m * N_TOK + n];
            c = lde(rpb_p, (size_t)idx * 8 + h, brp) + lde(mask_p, moff + m * N_TOK + n, bm);
          }
          t[ni] = f2bf(c);
        }
        cbp[r][0] = (unsigned)t[0] | ((unsigned)t[1] << 16);
        cbp[r][1] = (unsigned)t[2] | ((unsigned)t[3] << 16);
      }
    }

    // ================= QKV GEMM phase A: q,k (acc[4]) =================
    {
      f32x4 acc[4];
      #pragma unroll
      for (int j = 0; j < 4; ++j) acc[j] = (f32x4){0.f, 0.f, 0.f, 0.f};
      if (bw) {
        const u16* wp = (const u16*)qkvw_p;
        #pragma unroll
        for (int ks = 0; ks < 8; ++ks) {
          bf16x8 a = xf[ks];
          #pragma unroll
          for (int j = 0; j < 4; ++j) {
            int n = (j >> 1) * 256 + nb0 + (j & 1) * 16 + l15;
            bf16x8 b = *(const bf16x8*)(wp + (size_t)n * DIM + ks * 32 + quad * 8);
            acc[j] = __builtin_amdgcn_mfma_f32_16x16x32_bf16(a, b, acc[j], 0, 0, 0);
          }
        }
      } else {
        const float* wp = (const float*)qkvw_p;
        #pragma unroll
        for (int ks = 0; ks < 8; ++ks) {
          bf16x8 a = xf[ks];
          #pragma unroll
          for (int j = 0; j < 4; ++j) {
            int n = (j >> 1) * 256 + nb0 + (j & 1) * 16 + l15;
            bf16x8 b = cvt8(wp + (size_t)n * DIM + ks * 32 + quad * 8);
            acc[j] = __builtin_amdgcn_mfma_f32_16x16x32_bf16(a, b, acc[j], 0, 0, 0);
          }
        }
      }
      const float scale = 0.1767766952966369f;   // 1/sqrt(32)
      #pragma unroll
      for (int j = 0; j < 4; ++j) {
        int   n    = (j >> 1) * 256 + nb0 + (j & 1) * 16 + l15;
        float bias = lde(qkvb_p, n, bqb);
        int   lc   = (j & 1) * 16 + l15;
        if (j < 2) {
          #pragma unroll
          for (int r = 0; r < 4; ++r)
            qs[(mrow + r) * QK_S + lc] = f2bf((acc[j][r] + bias) * scale);
        } else {
          #pragma unroll
          for (int r = 0; r < 4; ++r)
            ksb[(mrow + r) * QK_S + lc] = f2bf(acc[j][r] + bias);
        }
      }
    }
    // ================= QKV GEMM phase B: v (acc[2]) =================
    {
      f32x4 av[2];
      av[0] = (f32x4){0.f, 0.f, 0.f, 0.f};
      av[1] = (f32x4){0.f, 0.f, 0.f, 0.f};
      if (bw) {
        const u16* wp = (const u16*)qkvw_p;
        #pragma unroll
        for (int ks = 0; ks < 8; ++ks) {
          bf16x8 a = xf[ks];
          #pragma unroll
          for (int j = 0; j < 2; ++j) {
            int n = 512 + nb0 + j * 16 + l15;
            bf16x8 b = *(const bf16x8*)(wp + (size_t)n * DIM + ks * 32 + quad * 8);
            av[j] = __builtin_amdgcn_mfma_f32_16x16x32_bf16(a, b, av[j], 0, 0, 0);
          }
        }
      } else {
        const float* wp = (const float*)qkvw_p;
        #pragma unroll
        for (int ks = 0; ks < 8; ++ks) {
          bf16x8 a = xf[ks];
          #pragma unroll
          for (int j = 0; j < 2; ++j) {
            int n = 512 + nb0 + j * 16 + l15;
            bf16x8 b = cvt8(wp + (size_t)n * DIM + ks * 32 + quad * 8);
            av[j] = __builtin_amdgcn_mfma_f32_16x16x32_bf16(a, b, av[j], 0, 0, 0);
          }
        }
      }
      #pragma unroll
      for (int j = 0; j < 2; ++j) {
        int   n    = 512 + nb0 + j * 16 + l15;
        float bias = lde(qkvb_p, n, bqb);
        int   lc   = j * 16 + l15;
        u16x4 pk;
        #pragma unroll
        for (int r = 0; r < 4; ++r) pk[r] = f2bf(av[j][r] + bias);
        *(u16x4*)&vtb[lc * VT_S + mrow] = pk;
      }
    }
    __syncthreads();   // the only barrier per head (k/vT dbuf'd across heads)

    // ================= S = q k^T =================
    f32x4 s[4];
    {
      bf16x8 aq = *(const bf16x8*)&qs[(16 * wv + l15) * QK_S + quad * 8];
      #pragma unroll
      for (int ni = 0; ni < 4; ++ni) {
        bf16x8 bk = *(const bf16x8*)&ksb[(ni * 16 + l15) * QK_S + quad * 8];
        s[ni] = __builtin_amdgcn_mfma_f32_16x16x32_bf16(aq, bk, (f32x4){0.f,0.f,0.f,0.f}, 0, 0, 0);
      }
    }
    // bias+mask (preloaded, packed) + softmax (row = 16-lane quad-group)
    float rs[4];
    #pragma unroll
    for (int r = 0; r < 4; ++r) {
      #pragma unroll
      for (int ni = 0; ni < 4; ++ni) {
        int   n = ni * 16 + l15;
        float c = bf2f((u16)(cbp[r][ni >> 1] >> ((ni & 1) * 16)));
        s[ni][r] = (n >= N_TOK) ? -1e30f : s[ni][r] + c;
      }
      float mx = fmaxf(fmaxf(s[0][r], s[1][r]), fmaxf(s[2][r], s[3][r]));
      #pragma unroll
      for (int d2 = 1; d2 < 16; d2 <<= 1) mx = fmaxf(mx, __shfl_xor(mx, d2));
      float sum = 0.f;
      #pragma unroll
      for (int ni = 0; ni < 4; ++ni) {
        float p = __expf(s[ni][r] - mx);
        s[ni][r] = p;
        sum += p;
      }
      #pragma unroll
      for (int d2 = 1; d2 < 16; d2 <<= 1) sum += __shfl_xor(sum, d2);
      rs[r] = sum;
      #pragma unroll
      for (int ni = 0; ni < 4; ++ni)
        Ps[(mrow + r) * P_S + ni * 16 + l15] = f2bf(s[ni][r]);
    }

    // ================= O = P V =================
    f32x4 o0 = {0.f,0.f,0.f,0.f}, o1 = {0.f,0.f,0.f,0.f};
    #pragma unroll
    for (int ks = 0; ks < 2; ++ks) {
      bf16x8 ap = *(const bf16x8*)&Ps[(16 * wv + l15) * P_S + ks * 32 + quad * 8];
      bf16x8 b0 = *(const bf16x8*)&vtb[(l15)      * VT_S + ks * 32 + quad * 8];
      bf16x8 b1 = *(const bf16x8*)&vtb[(16 + l15) * VT_S + ks * 32 + quad * 8];
      o0 = __builtin_amdgcn_mfma_f32_16x16x32_bf16(ap, b0, o0, 0, 0, 0);
      o1 = __builtin_amdgcn_mfma_f32_16x16x32_bf16(ap, b1, o1, 0, 0, 0);
    }
    #pragma unroll
    for (int r = 0; r < 4; ++r) {
      float inv = 1.f / rs[r];
      oh[(mrow + r) * OH_S + l15]      = f2bf(o0[r] * inv);
      oh[(mrow + r) * OH_S + 16 + l15] = f2bf(o1[r] * inv);
    }
    // transpose C-layout -> A-layout via same-wave LDS round trip; bank into named reg
    {
      bf16x8 ao = *(const bf16x8*)&oh[(16 * wv + l15) * OH_S + quad * 8];
      switch (h) {      // h is wave-uniform: cheap scalar branch, keeps oa* in VGPRs
        case 0: oa0 = ao; break;
        case 1: oa1 = ao; break;
        case 2: oa2 = ao; break;
        case 3: oa3 = ao; break;
        case 4: oa4 = ao; break;
        case 5: oa5 = ao; break;
        case 6: oa6 = ao; break;
        default: oa7 = ao; break;
      }
    }
  }

  // ================= deferred proj GEMM: pacc[ni] = sum_h oa_h * Wp_h =================
  f32x4 pacc[16];
  #pragma unroll
  for (int i = 0; i < 16; ++i) pacc[i] = (f32x4){0.f, 0.f, 0.f, 0.f};
  #pragma unroll
  for (int h = 0; h < 8; ++h) {
    bf16x8 ao;
    switch (h) {        // fully unrolled -> folds to a plain register copy
      case 0: ao = oa0; break;
      case 1: ao = oa1; break;
      case 2: ao = oa2; break;
      case 3: ao = oa3; break;
      case 4: ao = oa4; break;
      case 5: ao = oa5; break;
      case 6: ao = oa6; break;
      default: ao = oa7; break;
    }
    if (bpw) {
      const u16* pp = (const u16*)pjw_p;
      #pragma unroll
      for (int ni = 0; ni < 16; ++ni) {
        bf16x8 bp = *(const bf16x8*)(pp + (size_t)(ni * 16 + l15) * DIM + h * 32 + quad * 8);
        pacc[ni] = __builtin_amdgcn_mfma_f32_16x16x32_bf16(ao, bp, pacc[ni], 0, 0, 0);
      }
    } else {
      const float* pp = (const float*)pjw_p;
      #pragma unroll
      for (int ni = 0; ni < 16; ++ni) {
        bf16x8 bp = cvt8(pp + (size_t)(ni * 16 + l15) * DIM + h * 32 + quad * 8);
        pacc[ni] = __builtin_amdgcn_mfma_f32_16x16x32_bf16(ao, bp, pacc[ni], 0, 0, 0);
      }
    }
  }

  // ================= epilogue: + proj_b; output dtype follows x =================
  const size_t obase = (size_t)w * (N_TOK * DIM);
  if (bx) {
    u16* ow = (u16*)out + obase;
    #pragma unroll
    for (int r = 0; r < 4; ++r) {
      int m = mrow + r;
      if (m < N_TOK) {
        #pragma unroll
        for (int ni = 0; ni < 16; ++ni) {
          int col = ni * 16 + l15;
          ow[m * DIM + col] = f2bf(pacc[ni][r] + lde(pjb_p, col, bpb));
        }
      }
    }
  } else {
    float* ow = (float*)out + obase;
    #pragma unroll
    for (int r = 0; r < 4; ++r) {
      int m = mrow + r;
      if (m < N_TOK) {
        #pragma unroll
        for (int ni = 0; ni < 16; ++ni) {
          int col = ni * 16 + l15;
          ow[m * DIM + col] = pacc[ni][r] + lde(pjb_p, col, bpb);
        }
      }
    }
  }
}

extern "C" void kernel_launch(void* const* d_in, const int* in_sizes, int n_in,
                              void* d_out, int out_size, void* d_ws, size_t ws_size,
                              hipStream_t stream) {
  u16* wsu = (u16*)d_ws;
  int mode = 0;
  if (ws_size >= C2_TOT_U16 * 2) mode = 2;
  else if (ws_size >= WS_TOT_U16 * 2) mode = 1;

  auto cv = [&](const void* src, unsigned long long off, int n) {
    cvt_kernel<<<(n + 255) / 256, 256, 0, stream>>>(src, wsu + off, n);
  };

  if (mode == 2) {
    build_bias_kernel<<<NWIN, 256, 0, stream>>>(d_in[1], d_in[6], (const int*)d_in[7],
                                                wsu + C2_CMB_OFF);
    cv(d_in[2], C2_QKVW_OFF, 3 * DIM * DIM);
    cv(d_in[3], C2_QKVB_OFF, 3 * DIM);
    cv(d_in[4], C2_PROJW_OFF, DIM * DIM);
    cv(d_in[5], C2_PROJB_OFF, DIM);
  } else if (mode == 1) {
    cv(d_in[1], WS_MASK_OFF,  NWIN * N_TOK * N_TOK);
    cv(d_in[2], WS_QKVW_OFF,  3 * DIM * DIM);
    cv(d_in[3], WS_QKVB_OFF,  3 * DIM);
    cv(d_in[4], WS_PROJW_OFF, DIM * DIM);
    cv(d_in[5], WS_PROJB_OFF, DIM);
    cv(d_in[6], WS_RPB_OFF,   169 * 8);
  }
  winattn_kernel<<<4096, 256, 0, stream>>>(
      d_in[0], d_in[1], d_in[2], d_in[3], d_in[4], d_in[5], d_in[6],
      (const int*)d_in[7], d_out, wsu, mode);
}